// Round 12
// baseline (207.588 us; speedup 1.0000x reference)
//
#include <hip/hip_runtime.h>

#define NG 72

typedef _Float16 half2f __attribute__((ext_vector_type(2)));

__device__ __forceinline__ unsigned pkrtz(float a, float b) {
  return __builtin_bit_cast(unsigned, __builtin_amdgcn_cvt_pkrtz(a, b));
}
__device__ __forceinline__ float dot2(unsigned win, unsigned wgt, float acc) {
  return __builtin_amdgcn_fdot2(__builtin_bit_cast(half2f, win),
                                __builtin_bit_cast(half2f, wgt), acc, false);
}

// ---------------- prep: pack conv weights as half2 (ic-pairs) into d_ws ----
__global__ __launch_bounds__(256) void prep_k(const float* __restrict__ w1,
                                              const float* __restrict__ w2,
                                              const float* __restrict__ w3,
                                              unsigned* __restrict__ wf) {
  const int i = blockIdx.x * 256 + threadIdx.x;
  if (i < 28800) {
    const int t = i % 25, p = (i / 25) & 1, ocg = i / 50;
    const float* base = w1 + (size_t)ocg * 75 + t;
    const float a = base[p * 50];
    const float b = (p == 0) ? base[25] : 0.f;
    wf[i] = pkrtz(a, b);
  } else if (i < 70272) {
    const int j = i - 28800;
    const int t = j % 9, p = (j / 9) & 3, ocg = j / 36;
    const float* base = w2 + (size_t)ocg * 72 + t;
    wf[i] = pkrtz(base[2 * p * 9], base[(2 * p + 1) * 9]);
  } else if (i < 236160) {
    const int j = i - 70272;
    const int t = j % 9, p = (j / 9) & 7, ocg = j / 72;
    const float* base = w3 + (size_t)ocg * 144 + t;
    wf[i] = pkrtz(base[2 * p * 9], base[(2 * p + 1) * 9]);
  }
}

// ---------------- conv1: f16 ic-pair dot2, two sequential 4-oc passes -------
__global__ __launch_bounds__(256) void conv1_k(const float* __restrict__ x,
                                               const unsigned* __restrict__ wf,
                                               const float* __restrict__ bias,
                                               float* __restrict__ out) {
  const int blk = blockIdx.x;
  const int b = blk / (NG * 2), rem = blk % (NG * 2), g = rem >> 1, yh = rem & 1;
  const int y0 = yh ? 11 : 0;
  const int ny = yh ? 10 : 11;
  const int r0 = 2 * y0;
  const int nr = yh ? 24 : 26;
  __shared__ unsigned sxp[2][26][48];
  const float* xp = x + (size_t)(b * 216 + g * 3) * 2116;
  const int nf4 = (nr * 46) >> 2;
  const float4* q0 = (const float4*)(xp + r0 * 46);
  const float4* q1 = (const float4*)(xp + 2116 + r0 * 46);
  const float4* q2 = (const float4*)(xp + 2 * 2116 + r0 * 46);
  for (int i = threadIdx.x; i < nf4; i += 256) {
    const float4 a = q0[i], c1 = q1[i], c2 = q2[i];
#pragma unroll
    for (int j = 0; j < 4; j++) {
      const int k = 4 * i + j, r = k / 46, cc = k % 46;
      sxp[0][r][cc] = pkrtz((&a.x)[j], (&c1.x)[j]);
      sxp[1][r][cc] = pkrtz((&c2.x)[j], 0.f);
    }
  }
  __syncthreads();
  const unsigned* wgq = wf + (size_t)(g * 8) * 50;
  const float* bg = bias + g * 8;
  const int tid = threadIdx.x;
  if (tid < ny * 21) {
    const int yl = tid / 21, px = tid % 21;
    const int iy = 2 * yl, ix = 2 * px;
#pragma unroll 1   // two sequential 4-oc passes: acc 16 + winp live set small
    for (int half = 0; half < 2; half++) {
      float acc[4][4];
#pragma unroll
      for (int o = 0; o < 4; o++)
#pragma unroll
        for (int q = 0; q < 4; q++) acc[o][q] = 0.f;
#pragma unroll 1   // sequential ic-pair phases
      for (int p = 0; p < 2; p++) {
        unsigned winp[6][6];
#pragma unroll
        for (int r = 0; r < 6; r++)
#pragma unroll
          for (int c = 0; c < 6; c++) winp[r][c] = sxp[p][iy + r][ix + c];
#pragma unroll
        for (int o4 = 0; o4 < 4; o4++) {
          const int oc = half * 4 + o4;
          const unsigned* wq = wgq + (oc * 2 + p) * 25;   // uniform -> SGPR
#pragma unroll
          for (int ky = 0; ky < 5; ky++)
#pragma unroll
            for (int kx = 0; kx < 5; kx++) {
              const unsigned wv = wq[ky * 5 + kx];
              acc[o4][0] = dot2(winp[ky][kx],         wv, acc[o4][0]);
              acc[o4][1] = dot2(winp[ky][kx + 1],     wv, acc[o4][1]);
              acc[o4][2] = dot2(winp[ky + 1][kx],     wv, acc[o4][2]);
              acc[o4][3] = dot2(winp[ky + 1][kx + 1], wv, acc[o4][3]);
            }
        }
      }
#pragma unroll
      for (int o4 = 0; o4 < 4; o4++) {
        const int oc = half * 4 + o4;
        const float v = fmaxf(fmaxf(acc[o4][0], acc[o4][1]), fmaxf(acc[o4][2], acc[o4][3])) + bg[oc];
        out[(size_t)(b * 576 + g * 8 + oc) * 441 + (y0 + yl) * 21 + px] = fmaxf(v, 0.f);
      }
    }
  }
}

// ---------------- conv2: four sequential 4-oc passes ------------------------
#define C2_NBB 3
__global__ __launch_bounds__(256) void conv2_k(const float* __restrict__ x,
                                               const unsigned* __restrict__ wf,
                                               const float* __restrict__ bias,
                                               float* __restrict__ out) {
  const int g = blockIdx.x % NG, b0 = (blockIdx.x / NG) * C2_NBB;
  const int nbb = min(C2_NBB, 64 - b0);
  __shared__ unsigned sxp[C2_NBB][4][21][22];
  for (int bb = 0; bb < nbb; bb++) {
    const float* xp = x + (size_t)((b0 + bb) * 576 + g * 8) * 441;
    for (int i = threadIdx.x; i < 4 * 441; i += 256) {
      const int p = i / 441, e = i % 441, r = e / 21, c = e % 21;
      sxp[bb][p][r][c] = pkrtz(xp[2 * p * 441 + e], xp[(2 * p + 1) * 441 + e]);
    }
  }
  __syncthreads();
  const unsigned* wg = wf + (size_t)(g * 16) * 36;
  const float* bg = bias + g * 16;
  for (int u = threadIdx.x; u < nbb * 81; u += 256) {
    const int bb = u / 81, pp = u % 81, py = pp / 9, px = pp % 9;
    const int iy = 2 * py, ix = 2 * px;
#pragma unroll 1   // four sequential 4-oc passes
    for (int quarter = 0; quarter < 4; quarter++) {
      float acc[4][4];
#pragma unroll
      for (int o = 0; o < 4; o++)
#pragma unroll
        for (int q = 0; q < 4; q++) acc[o][q] = 0.f;
#pragma unroll 1   // sequential ic-pair phases
      for (int p = 0; p < 4; p++) {
        unsigned winp[4][4];
#pragma unroll
        for (int r = 0; r < 4; r++)
#pragma unroll
          for (int c = 0; c < 4; c++) winp[r][c] = sxp[bb][p][iy + r][ix + c];
#pragma unroll
        for (int o4 = 0; o4 < 4; o4++) {
          const int oc = quarter * 4 + o4;
          const unsigned* wq = wg + (oc * 4 + p) * 9;   // uniform -> SGPR
#pragma unroll
          for (int ky = 0; ky < 3; ky++)
#pragma unroll
            for (int kx = 0; kx < 3; kx++) {
              const unsigned wv = wq[ky * 3 + kx];
              acc[o4][0] = dot2(winp[ky][kx],         wv, acc[o4][0]);
              acc[o4][1] = dot2(winp[ky][kx + 1],     wv, acc[o4][1]);
              acc[o4][2] = dot2(winp[ky + 1][kx],     wv, acc[o4][2]);
              acc[o4][3] = dot2(winp[ky + 1][kx + 1], wv, acc[o4][3]);
            }
        }
      }
#pragma unroll
      for (int o4 = 0; o4 < 4; o4++) {
        const int oc = quarter * 4 + o4;
        const float v = fmaxf(fmaxf(acc[o4][0], acc[o4][1]), fmaxf(acc[o4][2], acc[o4][3])) + bg[oc];
        out[(size_t)((b0 + bb) * 1152 + g * 16 + oc) * 81 + pp] = fmaxf(v, 0.f);
      }
    }
  }
}

// ---------------- conv3: two sequential 4-oc passes per wave-ocg ------------
#define C3_NBB 7
__global__ __launch_bounds__(256) void conv3_k(const float* __restrict__ x,
                                               const unsigned* __restrict__ wf,
                                               const float* __restrict__ bias,
                                               float* __restrict__ out) {
  const int g = blockIdx.x % NG, b0 = (blockIdx.x / NG) * C3_NBB;
  const int nbb = min(C3_NBB, 64 - b0);
  __shared__ unsigned sxp[C3_NBB][8][9][10];
  for (int bb = 0; bb < nbb; bb++) {
    const float* xp = x + (size_t)((b0 + bb) * 1152 + g * 16) * 81;
    for (int i = threadIdx.x; i < 8 * 81; i += 256) {
      const int p = i / 81, e = i % 81, r = e / 9, c = e % 9;
      sxp[bb][p][r][c] = pkrtz(xp[2 * p * 81 + e], xp[(2 * p + 1) * 81 + e]);
    }
  }
  __syncthreads();
  const int ocg = __builtin_amdgcn_readfirstlane(threadIdx.x >> 6);
  const unsigned* wg = wf + ((size_t)(g * 32 + ocg * 8)) * 72;
  const float* bg = bias + g * 32 + ocg * 8;
  const int lane = threadIdx.x & 63;
  const int bb = lane / 9, pp = lane % 9;
  if (bb < nbb) {
    const int py = pp / 3, px = pp % 3, iy = 2 * py, ix = 2 * px;
#pragma unroll 1   // two sequential 4-oc passes
    for (int half = 0; half < 2; half++) {
      float acc[4][4];
#pragma unroll
      for (int o = 0; o < 4; o++)
#pragma unroll
        for (int q = 0; q < 4; q++) acc[o][q] = 0.f;
#pragma unroll 1
      for (int p = 0; p < 8; p++) {
        unsigned winp[4][4];
#pragma unroll
        for (int r = 0; r < 4; r++)
#pragma unroll
          for (int c = 0; c < 4; c++) winp[r][c] = sxp[bb][p][iy + r][ix + c];
#pragma unroll
        for (int o4 = 0; o4 < 4; o4++) {
          const int o8 = half * 4 + o4;
          const unsigned* wq = wg + (o8 * 8 + p) * 9;   // uniform -> SGPR
#pragma unroll
          for (int ky = 0; ky < 3; ky++)
#pragma unroll
            for (int kx = 0; kx < 3; kx++) {
              const unsigned wv = wq[ky * 3 + kx];
              acc[o4][0] = dot2(winp[ky][kx],         wv, acc[o4][0]);
              acc[o4][1] = dot2(winp[ky][kx + 1],     wv, acc[o4][1]);
              acc[o4][2] = dot2(winp[ky + 1][kx],     wv, acc[o4][2]);
              acc[o4][3] = dot2(winp[ky + 1][kx + 1], wv, acc[o4][3]);
            }
        }
      }
#pragma unroll
      for (int o4 = 0; o4 < 4; o4++) {
        const int o8 = half * 4 + o4;
        const float v = fmaxf(fmaxf(acc[o4][0], acc[o4][1]), fmaxf(acc[o4][2], acc[o4][3])) + bg[o8];
        out[(size_t)((b0 + bb) * 2304 + g * 32 + ocg * 8 + o8) * 9 + pp] = fmaxf(v, 0.f);
      }
    }
  }
}

// ---------------- fused block-diagonal linear1 (288->64) + linear2 (64->2) + bias
__global__ __launch_bounds__(256) void lin_k(const float* __restrict__ h,
                                             const float* __restrict__ w1,
                                             const float* __restrict__ w2,
                                             const float* __restrict__ b2,
                                             float* __restrict__ out) {
  const int g = blockIdx.x % NG, b0 = (blockIdx.x / NG) * 32;
  __shared__ float sw1[64 * 292];
  __shared__ float sf[32 * 300];
  __shared__ float so[32 * 65];
  __shared__ float sw2[2 * 64];
  __shared__ float sb2[2];
  for (int i = threadIdx.x; i < 64 * 288; i += 256) {
    const int o = i / 288, k = i % 288;
    sw1[o * 292 + k] = w1[(size_t)(g * 64 + o) * 20736 + g * 288 + k];
  }
  for (int i = threadIdx.x; i < 32 * 288; i += 256) {
    const int bb = i / 288, k = i % 288;
    sf[bb * 300 + k] = h[(size_t)(b0 + bb) * 20736 + g * 288 + k];
  }
  if (threadIdx.x < 128) {
    const int j = threadIdx.x >> 6, o = threadIdx.x & 63;
    sw2[j * 64 + o] = w2[(size_t)(g * 2 + j) * 4608 + g * 64 + o];
  }
  if (threadIdx.x < 2) sb2[threadIdx.x] = b2[g * 2 + threadIdx.x];
  __syncthreads();
  const int bp = threadIdx.x & 15, oq = threadIdx.x >> 4;
  const int o0 = 4 * oq;
  float acc[2][4];
#pragma unroll
  for (int i = 0; i < 2; i++)
#pragma unroll
    for (int j = 0; j < 4; j++) acc[i][j] = 0.f;
  for (int k4 = 0; k4 < 72; k4++) {
    const float4 f0 = *(const float4*)&sf[bp * 300 + 4 * k4];
    const float4 f1 = *(const float4*)&sf[(bp + 16) * 300 + 4 * k4];
#pragma unroll
    for (int j = 0; j < 4; j++) {
      const float4 wr = *(const float4*)&sw1[(o0 + j) * 292 + 4 * k4];
      acc[0][j] = fmaf(f0.x, wr.x, fmaf(f0.y, wr.y, fmaf(f0.z, wr.z, fmaf(f0.w, wr.w, acc[0][j]))));
      acc[1][j] = fmaf(f1.x, wr.x, fmaf(f1.y, wr.y, fmaf(f1.z, wr.z, fmaf(f1.w, wr.w, acc[1][j]))));
    }
  }
#pragma unroll
  for (int j = 0; j < 4; j++) {
    so[bp * 65 + o0 + j] = acc[0][j];
    so[(bp + 16) * 65 + o0 + j] = acc[1][j];
  }
  __syncthreads();
  if (threadIdx.x < 64) {
    const int bb = threadIdx.x >> 1, j = threadIdx.x & 1;
    float a = sb2[j];
#pragma unroll 8
    for (int o = 0; o < 64; o++) a = fmaf(so[bb * 65 + o], sw2[j * 64 + o], a);
    out[(b0 + bb) * 144 + g * 2 + j] = a;
  }
}

extern "C" void kernel_launch(void* const* d_in, const int* in_sizes, int n_in,
                              void* d_out, int out_size, void* d_ws, size_t ws_size,
                              hipStream_t stream) {
  const float* x   = (const float*)d_in[0];
  const float* w1  = (const float*)d_in[1];
  const float* b1  = (const float*)d_in[2];
  const float* w2  = (const float*)d_in[3];
  const float* b2  = (const float*)d_in[4];
  const float* w3  = (const float*)d_in[5];
  const float* b3  = (const float*)d_in[6];
  const float* l1w = (const float*)d_in[7];
  const float* l2w = (const float*)d_in[8];
  const float* l2b = (const float*)d_in[9];
  float* out = (float*)d_out;

  float* h1 = (float*)d_ws;          // 64*576*21*21
  float* h2 = h1 + 16257024;         // 64*1152*9*9
  float* h3 = h2 + 5971968;          // 64*2304*3*3
  unsigned* wf = (unsigned*)(h3 + 1327104);  // packed f16 weights (236160 u32)

  prep_k <<<dim3(923),         256, 0, stream>>>(w1, w2, w3, wf);
  conv1_k<<<dim3(64 * NG * 2), 256, 0, stream>>>(x,  wf,         b1, h1);
  conv2_k<<<dim3(22 * NG),     256, 0, stream>>>(h1, wf + 28800, b2, h2);
  conv3_k<<<dim3(10 * NG),     256, 0, stream>>>(h2, wf + 70272, b3, h3);
  lin_k  <<<dim3(2 * NG),      256, 0, stream>>>(h3, l1w, l2w, l2b, out);
}

// Round 13
// 206.193 us; speedup vs baseline: 1.0068x; 1.0068x over previous
//
#include <hip/hip_runtime.h>

#define NG 72

typedef _Float16 half2f __attribute__((ext_vector_type(2)));

__device__ __forceinline__ unsigned pkrtz(float a, float b) {
  return __builtin_bit_cast(unsigned, __builtin_amdgcn_cvt_pkrtz(a, b));
}
__device__ __forceinline__ float dot2(unsigned win, unsigned wgt, float acc) {
  return __builtin_amdgcn_fdot2(__builtin_bit_cast(half2f, win),
                                __builtin_bit_cast(half2f, wgt), acc, false);
}

// ---------------- prep: pack conv weights as half2 (ic-pairs) into d_ws ----
__global__ __launch_bounds__(256) void prep_k(const float* __restrict__ w1,
                                              const float* __restrict__ w2,
                                              const float* __restrict__ w3,
                                              unsigned* __restrict__ wf) {
  const int i = blockIdx.x * 256 + threadIdx.x;
  if (i < 28800) {
    const int t = i % 25, p = (i / 25) & 1, ocg = i / 50;
    const float* base = w1 + (size_t)ocg * 75 + t;
    const float a = base[p * 50];
    const float b = (p == 0) ? base[25] : 0.f;
    wf[i] = pkrtz(a, b);
  } else if (i < 70272) {
    const int j = i - 28800;
    const int t = j % 9, p = (j / 9) & 3, ocg = j / 36;
    const float* base = w2 + (size_t)ocg * 72 + t;
    wf[i] = pkrtz(base[2 * p * 9], base[(2 * p + 1) * 9]);
  } else if (i < 236160) {
    const int j = i - 70272;
    const int t = j % 9, p = (j / 9) & 7, ocg = j / 72;
    const float* base = w3 + (size_t)ocg * 144 + t;
    wf[i] = pkrtz(base[2 * p * 9], base[(2 * p + 1) * 9]);
  }
}

// ---------------- conv1: (64,216,46,46) -> k5 g72 (3->8) -> relu -> pool2 ----
// One 448-thread block per (b,g): 441 pooled outputs, 1.6% lane tail (vs 10.8%
// at 256/231), full 46-row tile staged once (no y-split redundancy).
// f16 ic-pair dot2, weights block-uniform -> SGPR s_load.
__global__ __launch_bounds__(448) void conv1_k(const float* __restrict__ x,
                                               const unsigned* __restrict__ wf,
                                               const float* __restrict__ bias,
                                               float* __restrict__ out) {
  const int b = blockIdx.x / NG, g = blockIdx.x % NG;
  __shared__ unsigned sxp[2][46][48];   // half2(ic-pair) per (r,c)
  const float* xp = x + (size_t)(b * 216 + g * 3) * 2116;
  const float4* q0 = (const float4*)xp;            // 529 float4 per plane, exact
  const float4* q1 = (const float4*)(xp + 2116);
  const float4* q2 = (const float4*)(xp + 2 * 2116);
  for (int i = threadIdx.x; i < 529; i += 448) {
    const float4 a = q0[i], c1 = q1[i], c2 = q2[i];
#pragma unroll
    for (int j = 0; j < 4; j++) {
      const int k = 4 * i + j, r = k / 46, cc = k % 46;
      sxp[0][r][cc] = pkrtz((&a.x)[j], (&c1.x)[j]);
      sxp[1][r][cc] = pkrtz((&c2.x)[j], 0.f);
    }
  }
  __syncthreads();
  const unsigned* wgq = wf + (size_t)(g * 8) * 50;   // [oc][p][25], uniform
  const float* bg = bias + g * 8;                    // uniform
  const int tid = threadIdx.x;
  if (tid < 441) {
    const int yl = tid / 21, px = tid % 21;
    const int iy = 2 * yl, ix = 2 * px;
    float acc[8][4];
#pragma unroll
    for (int o = 0; o < 8; o++)
#pragma unroll
      for (int q = 0; q < 4; q++) acc[o][q] = 0.f;
#pragma unroll 1   // sequential ic-pair phases: keep winp live range small
    for (int p = 0; p < 2; p++) {
      unsigned winp[6][6];
#pragma unroll
      for (int r = 0; r < 6; r++)
#pragma unroll
        for (int c = 0; c < 6; c++) winp[r][c] = sxp[p][iy + r][ix + c];
#pragma unroll
      for (int oc = 0; oc < 8; oc++) {
        const unsigned* wq = wgq + (oc * 2 + p) * 25;   // uniform -> SGPR
#pragma unroll
        for (int ky = 0; ky < 5; ky++)
#pragma unroll
          for (int kx = 0; kx < 5; kx++) {
            const unsigned wv = wq[ky * 5 + kx];
            acc[oc][0] = dot2(winp[ky][kx],         wv, acc[oc][0]);
            acc[oc][1] = dot2(winp[ky][kx + 1],     wv, acc[oc][1]);
            acc[oc][2] = dot2(winp[ky + 1][kx],     wv, acc[oc][2]);
            acc[oc][3] = dot2(winp[ky + 1][kx + 1], wv, acc[oc][3]);
          }
      }
    }
#pragma unroll
    for (int oc = 0; oc < 8; oc++) {
      const float v = fmaxf(fmaxf(acc[oc][0], acc[oc][1]), fmaxf(acc[oc][2], acc[oc][3])) + bg[oc];
      out[(size_t)(b * 576 + g * 8 + oc) * 441 + yl * 21 + px] = fmaxf(v, 0.f);
    }
  }
}

// ---------------- conv2: (64,576,21,21) -> k3 (8->16) -> relu -> pool2 ------
#define C2_NBB 3
__global__ __launch_bounds__(256) void conv2_k(const float* __restrict__ x,
                                               const unsigned* __restrict__ wf,
                                               const float* __restrict__ bias,
                                               float* __restrict__ out) {
  const int g = blockIdx.x % NG, b0 = (blockIdx.x / NG) * C2_NBB;
  const int nbb = min(C2_NBB, 64 - b0);
  __shared__ unsigned sxp[C2_NBB][4][21][22];   // half2 ic-pairs
  for (int bb = 0; bb < nbb; bb++) {
    const float* xp = x + (size_t)((b0 + bb) * 576 + g * 8) * 441;
    for (int i = threadIdx.x; i < 4 * 441; i += 256) {
      const int p = i / 441, e = i % 441, r = e / 21, c = e % 21;
      sxp[bb][p][r][c] = pkrtz(xp[2 * p * 441 + e], xp[(2 * p + 1) * 441 + e]);
    }
  }
  __syncthreads();
  const unsigned* wg = wf + (size_t)(g * 16) * 36;   // [oc][p][9], uniform
  const float* bg = bias + g * 16;                   // uniform
  for (int u = threadIdx.x; u < nbb * 81; u += 256) {
    const int bb = u / 81, pp = u % 81, py = pp / 9, px = pp % 9;
    const int iy = 2 * py, ix = 2 * px;
    float acc[16][4];
#pragma unroll
    for (int o = 0; o < 16; o++)
#pragma unroll
      for (int q = 0; q < 4; q++) acc[o][q] = 0.f;
#pragma unroll 1   // sequential ic-pair phases
    for (int p = 0; p < 4; p++) {
      unsigned winp[4][4];
#pragma unroll
      for (int r = 0; r < 4; r++)
#pragma unroll
        for (int c = 0; c < 4; c++) winp[r][c] = sxp[bb][p][iy + r][ix + c];
#pragma unroll
      for (int oc = 0; oc < 16; oc++) {
        const unsigned* wq = wg + (oc * 4 + p) * 9;   // uniform -> SGPR
#pragma unroll
        for (int ky = 0; ky < 3; ky++)
#pragma unroll
          for (int kx = 0; kx < 3; kx++) {
            const unsigned wv = wq[ky * 3 + kx];
            acc[oc][0] = dot2(winp[ky][kx],         wv, acc[oc][0]);
            acc[oc][1] = dot2(winp[ky][kx + 1],     wv, acc[oc][1]);
            acc[oc][2] = dot2(winp[ky + 1][kx],     wv, acc[oc][2]);
            acc[oc][3] = dot2(winp[ky + 1][kx + 1], wv, acc[oc][3]);
          }
      }
    }
#pragma unroll
    for (int oc = 0; oc < 16; oc++) {
      const float v = fmaxf(fmaxf(acc[oc][0], acc[oc][1]), fmaxf(acc[oc][2], acc[oc][3])) + bg[oc];
      out[(size_t)((b0 + bb) * 1152 + g * 16 + oc) * 81 + pp] = fmaxf(v, 0.f);
    }
  }
}

// ---------------- conv3: (64,1152,9,9) -> k3 (16->32) -> relu -> pool2 ------
#define C3_NBB 7
__global__ __launch_bounds__(256) void conv3_k(const float* __restrict__ x,
                                               const unsigned* __restrict__ wf,
                                               const float* __restrict__ bias,
                                               float* __restrict__ out) {
  const int g = blockIdx.x % NG, b0 = (blockIdx.x / NG) * C3_NBB;
  const int nbb = min(C3_NBB, 64 - b0);
  __shared__ unsigned sxp[C3_NBB][8][9][10];   // half2 ic-pairs, pitch 10
  for (int bb = 0; bb < nbb; bb++) {
    const float* xp = x + (size_t)((b0 + bb) * 1152 + g * 16) * 81;
    for (int i = threadIdx.x; i < 8 * 81; i += 256) {
      const int p = i / 81, e = i % 81, r = e / 9, c = e % 9;
      sxp[bb][p][r][c] = pkrtz(xp[2 * p * 81 + e], xp[(2 * p + 1) * 81 + e]);
    }
  }
  __syncthreads();
  const int ocg = __builtin_amdgcn_readfirstlane(threadIdx.x >> 6);  // uniform
  const unsigned* wg = wf + ((size_t)(g * 32 + ocg * 8)) * 72;       // [oc][p][9]
  const float* bg = bias + g * 32 + ocg * 8;                         // uniform
  const int lane = threadIdx.x & 63;
  const int bb = lane / 9, pp = lane % 9;
  if (bb < nbb) {
    const int py = pp / 3, px = pp % 3, iy = 2 * py, ix = 2 * px;
    float acc[8][4];
#pragma unroll
    for (int o = 0; o < 8; o++)
#pragma unroll
      for (int q = 0; q < 4; q++) acc[o][q] = 0.f;
#pragma unroll 1
    for (int p = 0; p < 8; p++) {
      unsigned winp[4][4];
#pragma unroll
      for (int r = 0; r < 4; r++)
#pragma unroll
        for (int c = 0; c < 4; c++) winp[r][c] = sxp[bb][p][iy + r][ix + c];
#pragma unroll
      for (int o8 = 0; o8 < 8; o8++) {
        const unsigned* wq = wg + (o8 * 8 + p) * 9;   // uniform -> SGPR
#pragma unroll
        for (int ky = 0; ky < 3; ky++)
#pragma unroll
          for (int kx = 0; kx < 3; kx++) {
            const unsigned wv = wq[ky * 3 + kx];
            acc[o8][0] = dot2(winp[ky][kx],         wv, acc[o8][0]);
            acc[o8][1] = dot2(winp[ky][kx + 1],     wv, acc[o8][1]);
            acc[o8][2] = dot2(winp[ky + 1][kx],     wv, acc[o8][2]);
            acc[o8][3] = dot2(winp[ky + 1][kx + 1], wv, acc[o8][3]);
          }
      }
    }
#pragma unroll
    for (int o8 = 0; o8 < 8; o8++) {
      const float v = fmaxf(fmaxf(acc[o8][0], acc[o8][1]), fmaxf(acc[o8][2], acc[o8][3])) + bg[o8];
      out[(size_t)((b0 + bb) * 2304 + g * 32 + ocg * 8 + o8) * 9 + pp] = fmaxf(v, 0.f);
    }
  }
}

// ---------------- fused block-diagonal linear1 (288->64) + linear2 (64->2) + bias
__global__ __launch_bounds__(256) void lin_k(const float* __restrict__ h,
                                             const float* __restrict__ w1,
                                             const float* __restrict__ w2,
                                             const float* __restrict__ b2,
                                             float* __restrict__ out) {
  const int g = blockIdx.x % NG, b0 = (blockIdx.x / NG) * 32;
  __shared__ float sw1[64 * 292];
  __shared__ float sf[32 * 300];
  __shared__ float so[32 * 65];
  __shared__ float sw2[2 * 64];
  __shared__ float sb2[2];
  for (int i = threadIdx.x; i < 64 * 288; i += 256) {
    const int o = i / 288, k = i % 288;
    sw1[o * 292 + k] = w1[(size_t)(g * 64 + o) * 20736 + g * 288 + k];
  }
  for (int i = threadIdx.x; i < 32 * 288; i += 256) {
    const int bb = i / 288, k = i % 288;
    sf[bb * 300 + k] = h[(size_t)(b0 + bb) * 20736 + g * 288 + k];
  }
  if (threadIdx.x < 128) {
    const int j = threadIdx.x >> 6, o = threadIdx.x & 63;
    sw2[j * 64 + o] = w2[(size_t)(g * 2 + j) * 4608 + g * 64 + o];
  }
  if (threadIdx.x < 2) sb2[threadIdx.x] = b2[g * 2 + threadIdx.x];
  __syncthreads();
  const int bp = threadIdx.x & 15, oq = threadIdx.x >> 4;
  const int o0 = 4 * oq;
  float acc[2][4];
#pragma unroll
  for (int i = 0; i < 2; i++)
#pragma unroll
    for (int j = 0; j < 4; j++) acc[i][j] = 0.f;
  for (int k4 = 0; k4 < 72; k4++) {
    const float4 f0 = *(const float4*)&sf[bp * 300 + 4 * k4];
    const float4 f1 = *(const float4*)&sf[(bp + 16) * 300 + 4 * k4];
#pragma unroll
    for (int j = 0; j < 4; j++) {
      const float4 wr = *(const float4*)&sw1[(o0 + j) * 292 + 4 * k4];
      acc[0][j] = fmaf(f0.x, wr.x, fmaf(f0.y, wr.y, fmaf(f0.z, wr.z, fmaf(f0.w, wr.w, acc[0][j]))));
      acc[1][j] = fmaf(f1.x, wr.x, fmaf(f1.y, wr.y, fmaf(f1.z, wr.z, fmaf(f1.w, wr.w, acc[1][j]))));
    }
  }
#pragma unroll
  for (int j = 0; j < 4; j++) {
    so[bp * 65 + o0 + j] = acc[0][j];
    so[(bp + 16) * 65 + o0 + j] = acc[1][j];
  }
  __syncthreads();
  if (threadIdx.x < 64) {
    const int bb = threadIdx.x >> 1, j = threadIdx.x & 1;
    float a = sb2[j];
#pragma unroll 8
    for (int o = 0; o < 64; o++) a = fmaf(so[bb * 65 + o], sw2[j * 64 + o], a);
    out[(b0 + bb) * 144 + g * 2 + j] = a;
  }
}

extern "C" void kernel_launch(void* const* d_in, const int* in_sizes, int n_in,
                              void* d_out, int out_size, void* d_ws, size_t ws_size,
                              hipStream_t stream) {
  const float* x   = (const float*)d_in[0];
  const float* w1  = (const float*)d_in[1];
  const float* b1  = (const float*)d_in[2];
  const float* w2  = (const float*)d_in[3];
  const float* b2  = (const float*)d_in[4];
  const float* w3  = (const float*)d_in[5];
  const float* b3  = (const float*)d_in[6];
  const float* l1w = (const float*)d_in[7];
  const float* l2w = (const float*)d_in[8];
  const float* l2b = (const float*)d_in[9];
  float* out = (float*)d_out;

  float* h1 = (float*)d_ws;          // 64*576*21*21
  float* h2 = h1 + 16257024;         // 64*1152*9*9
  float* h3 = h2 + 5971968;          // 64*2304*3*3
  unsigned* wf = (unsigned*)(h3 + 1327104);  // packed f16 weights (236160 u32)

  prep_k <<<dim3(923),     256, 0, stream>>>(w1, w2, w3, wf);
  conv1_k<<<dim3(64 * NG), 448, 0, stream>>>(x,  wf,         b1, h1);
  conv2_k<<<dim3(22 * NG), 256, 0, stream>>>(h1, wf + 28800, b2, h2);
  conv3_k<<<dim3(10 * NG), 256, 0, stream>>>(h2, wf + 70272, b3, h3);
  lin_k  <<<dim3(2 * NG),  256, 0, stream>>>(h3, l1w, l2w, l2b, out);
}